// Round 1
// baseline (614.491 us; speedup 1.0000x reference)
//
#include <hip/hip_runtime.h>
#include <hip/hip_bf16.h>

typedef __attribute__((ext_vector_type(8))) short short8;   // 8 bf16 = 4 VGPRs (MFMA A/B frag)
typedef __attribute__((ext_vector_type(4))) float f32x4;    // MFMA C/D frag

#define MFMA(a, b, c) __builtin_amdgcn_mfma_f32_16x16x32_bf16((a), (b), (c), 0, 0, 0)

__device__ __forceinline__ unsigned short f2bf(float f) {
    unsigned int u = __float_as_uint(f);
    u += 0x7fffu + ((u >> 16) & 1u);          // round-to-nearest-even
    return (unsigned short)(u >> 16);
}

__device__ __forceinline__ float gelu_exact(float x) {
    return 0.5f * x * (1.0f + erff(x * 0.70710678118654752440f));
}

// Load one 8-k-contiguous B fragment (bf16) from a row-major [K][ldn] fp32 weight,
// transposing on the fly: r[u] = W[k0+u][n].  B-operand mapping: n = lane&15, k = quad*8+u.
__device__ __forceinline__ short8 load_bfrag(const float* __restrict__ w, int k0, int n, int ldn) {
    short8 r;
#pragma unroll
    for (int u = 0; u < 8; ++u)
        r[u] = (short)f2bf(w[(k0 + u) * ldn + n]);
    return r;
}

// ---------------------------------------------------------------------------
// Head 1: structure predictor.
// per edge e: ef = [x[row], x[col]] (K=128); h = LN(ef@W1+b1)*g+be; out = gelu(h)@w2 + b2
// Tile: 128 edges x 256 cols, K=128.  8 waves in 2x4 grid, each wave 64x64.
// W1^T fragments live in registers (persistent across tiles); A (gathered edges) in LDS.
// ---------------------------------------------------------------------------
__global__ __launch_bounds__(512, 2)
void edge_head_kernel(const float* __restrict__ x, const int* __restrict__ ei,
                      const float* __restrict__ w1, const float* __restrict__ b1,
                      const float* __restrict__ g, const float* __restrict__ be,
                      const float* __restrict__ w2, const float* __restrict__ b2,
                      float* __restrict__ out, int E) {
    constexpr int KP = 136;                       // 128 + 8 pad: row stride 272B -> 2-way (free)
    __shared__ unsigned short sA[128 * KP];       // 34.8 KB gathered edge features (bf16)
    __shared__ float rsum[128 * 4];
    __shared__ float rssq[128 * 4];
    __shared__ float spL[128 * 4];

    const int tid = threadIdx.x;
    const int wave = tid >> 6, lane = tid & 63;
    const int l15 = lane & 15, quad = lane >> 4;
    const int rw = wave >> 2, cw = wave & 3;      // wave grid: 2 row-blocks x 4 col-blocks

    // persistent W1^T fragments: cols cw*64 + 16j + l15, K-slabs kk*32 + quad*8
    short8 breg[4][4];
#pragma unroll
    for (int j = 0; j < 4; ++j)
#pragma unroll
        for (int kk = 0; kk < 4; ++kk)
            breg[j][kk] = load_bfrag(w1, kk * 32 + quad * 8, cw * 64 + 16 * j + l15, 256);

    float b1v[4], gv[4], bev[4], w2v[4];
#pragma unroll
    for (int j = 0; j < 4; ++j) {
        int c = cw * 64 + 16 * j + l15;
        b1v[j] = b1[c]; gv[j] = g[c]; bev[j] = be[c]; w2v[j] = w2[c];
    }
    const float b2v = b2[0];

    const int ntiles = (E + 127) >> 7;
    const int eLoc = tid >> 2, p = tid & 3;       // 4 threads per edge, 32 floats each

    float4 pf[8];
    auto issue = [&](int t) {                     // prefetch gather for tile t into regs
        int e = t * 128 + eLoc; if (e >= E) e = E - 1;
        int idx = ei[(p >> 1) * E + e];           // p<2: row node, p>=2: col node
        const float4* src = (const float4*)(x + (long)idx * 64 + (p & 1) * 32);
#pragma unroll
        for (int u = 0; u < 8; ++u) pf[u] = src[u];
    };

    int t = blockIdx.x;
    if (t < ntiles) issue(t);
    for (; t < ntiles; t += gridDim.x) {
        // stage prefetched tile into LDS (bf16)
        unsigned short* dst = &sA[eLoc * KP + p * 32];
#pragma unroll
        for (int u = 0; u < 8; ++u) {
            ushort4 h;
            h.x = f2bf(pf[u].x); h.y = f2bf(pf[u].y);
            h.z = f2bf(pf[u].z); h.w = f2bf(pf[u].w);
            *(ushort4*)(dst + 4 * u) = h;
        }
        __syncthreads();                           // B1: sA ready
        if (t + (int)gridDim.x < ntiles) issue(t + (int)gridDim.x);  // overlap with MFMA

        f32x4 acc[4][4];
#pragma unroll
        for (int i = 0; i < 4; ++i)
#pragma unroll
            for (int j = 0; j < 4; ++j)
                acc[i][j] = (f32x4){0.f, 0.f, 0.f, 0.f};

#pragma unroll
        for (int kk = 0; kk < 4; ++kk) {
            short8 a[4];
#pragma unroll
            for (int i = 0; i < 4; ++i)
                a[i] = *(const short8*)&sA[(rw * 64 + 16 * i + l15) * KP + kk * 32 + quad * 8];
#pragma unroll
            for (int i = 0; i < 4; ++i)
#pragma unroll
                for (int j = 0; j < 4; ++j)
                    acc[i][j] = MFMA(a[i], breg[j][kk], acc[i][j]);
        }

        // per-row partial sums over this wave's 64 cols (LN stats span 4 col-waves)
#pragma unroll
        for (int i = 0; i < 4; ++i)
#pragma unroll
            for (int r = 0; r < 4; ++r) {
                float s = 0.f, ss = 0.f;
#pragma unroll
                for (int j = 0; j < 4; ++j) {
                    float v = acc[i][j][r] + b1v[j];
                    s += v; ss += v * v;
                }
#pragma unroll
                for (int m = 8; m >= 1; m >>= 1) {
                    s += __shfl_xor(s, m, 64);
                    ss += __shfl_xor(ss, m, 64);
                }
                if (l15 == 0) {
                    int row = rw * 64 + 16 * i + quad * 4 + r;   // C/D: row = quad*4+reg
                    rsum[row * 4 + cw] = s;
                    rssq[row * 4 + cw] = ss;
                }
            }
        __syncthreads();                           // B2: partials ready

#pragma unroll
        for (int i = 0; i < 4; ++i)
#pragma unroll
            for (int r = 0; r < 4; ++r) {
                int row = rw * 64 + 16 * i + quad * 4 + r;
                float s  = rsum[row*4+0] + rsum[row*4+1] + rsum[row*4+2] + rsum[row*4+3];
                float ss = rssq[row*4+0] + rssq[row*4+1] + rssq[row*4+2] + rssq[row*4+3];
                float mean = s * (1.f / 256.f);
                float var  = ss * (1.f / 256.f) - mean * mean;
                float rstd = rsqrtf(var + 1e-5f);
                float spp = 0.f;
#pragma unroll
                for (int j = 0; j < 4; ++j) {
                    float v = acc[i][j][r] + b1v[j];
                    float xn = (v - mean) * rstd * gv[j] + bev[j];
                    spp += gelu_exact(xn) * w2v[j];
                }
#pragma unroll
                for (int m = 8; m >= 1; m >>= 1)
                    spp += __shfl_xor(spp, m, 64);
                if (l15 == 0) spL[row * 4 + cw] = spp;
            }
        __syncthreads();                           // B3: spL ready

        int e = t * 128 + tid;
        if (tid < 128 && e < E)
            out[e] = spL[tid*4+0] + spL[tid*4+1] + spL[tid*4+2] + spL[tid*4+3] + b2v;
    }
}

// ---------------------------------------------------------------------------
// Heads 2/3: fused row-MLP  out = gelu(LN(x@W1+b1)*g+be) @ W2 + b2
// Tile 64 rows; 4 waves each own N1/4 cols of GEMM1 and N2/4 cols of GEMM2.
// Both weights' fragments cached in registers; LDS holds A-tile then gelu(h) (A-layout).
// ---------------------------------------------------------------------------
template<int K, int N1, int N2>
__global__ __launch_bounds__(256, 2)
void mlp_head_kernel(const float* __restrict__ x,
                     const float* __restrict__ w1, const float* __restrict__ b1,
                     const float* __restrict__ g, const float* __restrict__ be,
                     const float* __restrict__ w2, const float* __restrict__ b2,
                     float* __restrict__ out, int Nrows) {
    constexpr int KP   = K + 8;
    constexpr int N1P  = N1 + 8;
    constexpr int JT1  = N1 / 64;     // GEMM1 col-tiles per wave
    constexpr int JT2  = N2 / 64 > 0 ? N2 / 64 : 1;
    constexpr int CPW1 = N1 / 4;
    constexpr int CPW2 = N2 / 4;
    constexpr int KK1  = K / 32;
    constexpr int KK2  = N1 / 32;

    __shared__ unsigned short sS[64 * N1P];   // union: A [64][KP] then gelu(h) [64][N1P]
    __shared__ float rsum[64 * 4], rssq[64 * 4];

    const int tid = threadIdx.x;
    const int wave = tid >> 6, lane = tid & 63;
    const int l15 = lane & 15, quad = lane >> 4;

    short8 breg1[JT1][KK1];
#pragma unroll
    for (int j = 0; j < JT1; ++j)
#pragma unroll
        for (int kk = 0; kk < KK1; ++kk)
            breg1[j][kk] = load_bfrag(w1, kk * 32 + quad * 8, CPW1 * wave + 16 * j + l15, N1);
    short8 breg2[JT2][KK2];
#pragma unroll
    for (int j = 0; j < JT2; ++j)
#pragma unroll
        for (int kk = 0; kk < KK2; ++kk)
            breg2[j][kk] = load_bfrag(w2, kk * 32 + quad * 8, CPW2 * wave + 16 * j + l15, N2);

    float b1v[JT1], gv[JT1], bev[JT1];
#pragma unroll
    for (int j = 0; j < JT1; ++j) {
        int c = CPW1 * wave + 16 * j + l15;
        b1v[j] = b1[c]; gv[j] = g[c]; bev[j] = be[c];
    }
    float b2v[JT2];
#pragma unroll
    for (int j = 0; j < JT2; ++j) b2v[j] = b2[CPW2 * wave + 16 * j + l15];

    const int ntiles = (Nrows + 63) >> 6;
    const int m0 = tid >> 2, p = tid & 3;     // 4 threads per row for A staging

    for (int t = blockIdx.x; t < ntiles; t += gridDim.x) {
        const int r0 = t << 6;
        __syncthreads();                       // B0: prev-iter GEMM2 reads of sS done
        {
            int rowg = r0 + m0; if (rowg >= Nrows) rowg = Nrows - 1;
            const float4* src = (const float4*)(x + (long)rowg * K + p * (K / 4));
            unsigned short* dst = &sS[m0 * KP + p * (K / 4)];
#pragma unroll
            for (int u = 0; u < K / 16; ++u) {
                float4 f = src[u];
                ushort4 h; h.x = f2bf(f.x); h.y = f2bf(f.y); h.z = f2bf(f.z); h.w = f2bf(f.w);
                *(ushort4*)(dst + 4 * u) = h;
            }
        }
        __syncthreads();                       // B1: A ready

        f32x4 acc1[4][JT1];
#pragma unroll
        for (int i = 0; i < 4; ++i)
#pragma unroll
            for (int j = 0; j < JT1; ++j)
                acc1[i][j] = (f32x4){0.f, 0.f, 0.f, 0.f};

#pragma unroll
        for (int kk = 0; kk < KK1; ++kk) {
            short8 a[4];
#pragma unroll
            for (int i = 0; i < 4; ++i)
                a[i] = *(const short8*)&sS[(16 * i + l15) * KP + kk * 32 + quad * 8];
#pragma unroll
            for (int i = 0; i < 4; ++i)
#pragma unroll
                for (int j = 0; j < JT1; ++j)
                    acc1[i][j] = MFMA(a[i], breg1[j][kk], acc1[i][j]);
        }

#pragma unroll
        for (int i = 0; i < 4; ++i)
#pragma unroll
            for (int r = 0; r < 4; ++r) {
                float s = 0.f, ss = 0.f;
#pragma unroll
                for (int j = 0; j < JT1; ++j) {
                    float v = acc1[i][j][r] + b1v[j];
                    s += v; ss += v * v;
                }
#pragma unroll
                for (int m = 8; m >= 1; m >>= 1) {
                    s += __shfl_xor(s, m, 64);
                    ss += __shfl_xor(ss, m, 64);
                }
                if (l15 == 0) {
                    int row = 16 * i + quad * 4 + r;
                    rsum[row * 4 + wave] = s; rssq[row * 4 + wave] = ss;
                }
            }
        __syncthreads();                       // B2: LN partials ready (A also fully consumed)

#pragma unroll
        for (int i = 0; i < 4; ++i)
#pragma unroll
            for (int r = 0; r < 4; ++r) {
                int row = 16 * i + quad * 4 + r;
                float s  = rsum[row*4+0] + rsum[row*4+1] + rsum[row*4+2] + rsum[row*4+3];
                float ss = rssq[row*4+0] + rssq[row*4+1] + rssq[row*4+2] + rssq[row*4+3];
                float mean = s * (1.f / (float)N1);
                float var  = ss * (1.f / (float)N1) - mean * mean;
                float rstd = rsqrtf(var + 1e-5f);
#pragma unroll
                for (int j = 0; j < JT1; ++j) {
                    float v = acc1[i][j][r] + b1v[j];
                    float xn = (v - mean) * rstd * gv[j] + bev[j];
                    sS[row * N1P + CPW1 * wave + 16 * j + l15] = f2bf(gelu_exact(xn));
                }
            }
        __syncthreads();                       // B3: gelu(h) ready in A-layout

        f32x4 acc2[4][JT2];
#pragma unroll
        for (int i = 0; i < 4; ++i)
#pragma unroll
            for (int j = 0; j < JT2; ++j)
                acc2[i][j] = (f32x4){0.f, 0.f, 0.f, 0.f};

#pragma unroll
        for (int kk = 0; kk < KK2; ++kk) {
            short8 a[4];
#pragma unroll
            for (int i = 0; i < 4; ++i)
                a[i] = *(const short8*)&sS[(16 * i + l15) * N1P + kk * 32 + quad * 8];
#pragma unroll
            for (int i = 0; i < 4; ++i)
#pragma unroll
                for (int j = 0; j < JT2; ++j)
                    acc2[i][j] = MFMA(a[i], breg2[j][kk], acc2[i][j]);
        }

#pragma unroll
        for (int i = 0; i < 4; ++i)
#pragma unroll
            for (int r = 0; r < 4; ++r) {
                int rowg = r0 + 16 * i + quad * 4 + r;
                if (rowg < Nrows) {
#pragma unroll
                    for (int j = 0; j < JT2; ++j)
                        out[(long)rowg * N2 + CPW2 * wave + 16 * j + l15] = acc2[i][j][r] + b2v[j];
                }
            }
    }
}

extern "C" void kernel_launch(void* const* d_in, const int* in_sizes, int n_in,
                              void* d_out, int out_size, void* d_ws, size_t ws_size,
                              hipStream_t stream) {
    const float* x     = (const float*)d_in[0];
    const int*   ei    = (const int*)d_in[1];
    const float* sp_w1 = (const float*)d_in[2];
    const float* sp_b1 = (const float*)d_in[3];
    const float* sp_g  = (const float*)d_in[4];
    const float* sp_be = (const float*)d_in[5];
    const float* sp_w2 = (const float*)d_in[6];
    const float* sp_b2 = (const float*)d_in[7];
    const float* fr_w1 = (const float*)d_in[8];
    const float* fr_b1 = (const float*)d_in[9];
    const float* fr_g  = (const float*)d_in[10];
    const float* fr_be = (const float*)d_in[11];
    const float* fr_w2 = (const float*)d_in[12];
    const float* fr_b2 = (const float*)d_in[13];
    const float* ph_w1 = (const float*)d_in[14];
    const float* ph_b1 = (const float*)d_in[15];
    const float* ph_g  = (const float*)d_in[16];
    const float* ph_be = (const float*)d_in[17];
    const float* ph_w2 = (const float*)d_in[18];
    const float* ph_b2 = (const float*)d_in[19];

    const int N = in_sizes[0] / 64;
    const int E = in_sizes[1] / 2;

    float* out_sp   = (float*)d_out;
    float* out_rec  = out_sp + E;
    float* out_proj = out_rec + (size_t)N * 64;

    int etiles = (E + 127) / 128;
    int egrid  = etiles < 512 ? etiles : 512;
    edge_head_kernel<<<dim3(egrid), dim3(512), 0, stream>>>(
        x, ei, sp_w1, sp_b1, sp_g, sp_be, sp_w2, sp_b2, out_sp, E);

    int mtiles = (N + 63) / 64;
    int mgrid  = mtiles < 512 ? mtiles : 512;
    mlp_head_kernel<64, 128, 64><<<dim3(mgrid), dim3(256), 0, stream>>>(
        x, fr_w1, fr_b1, fr_g, fr_be, fr_w2, fr_b2, out_rec, N);
    mlp_head_kernel<64, 256, 128><<<dim3(mgrid), dim3(256), 0, stream>>>(
        x, ph_w1, ph_b1, ph_g, ph_be, ph_w2, ph_b2, out_proj, N);
}

// Round 2
// 548.992 us; speedup vs baseline: 1.1193x; 1.1193x over previous
//
#include <hip/hip_runtime.h>
#include <hip/hip_bf16.h>

typedef __attribute__((ext_vector_type(8))) short short8;   // 8 bf16 = 4 VGPRs (MFMA A/B frag)
typedef __attribute__((ext_vector_type(4))) float f32x4;    // MFMA C/D frag

#define MFMA(a, b, c) __builtin_amdgcn_mfma_f32_16x16x32_bf16((a), (b), (c), 0, 0, 0)

__device__ __forceinline__ unsigned short f2bf(float f) {
    unsigned int u = __float_as_uint(f);
    u += 0x7fffu + ((u >> 16) & 1u);          // round-to-nearest-even
    return (unsigned short)(u >> 16);
}

// erf via Abramowitz-Stegun 7.1.26 (max abs err 1.5e-7), hardware exp + rcp.
// ~12 VALU ops vs libm erff's ~50.
__device__ __forceinline__ float erf_fast(float z) {
    float az = fabsf(z);
    float t = __builtin_amdgcn_rcpf(__builtin_fmaf(0.3275911f, az, 1.0f));
    float p = t * __builtin_fmaf(t,
                 __builtin_fmaf(t,
                   __builtin_fmaf(t,
                     __builtin_fmaf(t, 1.061405429f, -1.453152027f),
                     1.421413741f),
                   -0.284496736f),
                 0.254829592f);
    float e = __expf(-az * az);               // v_exp_f32 (native)
    float r = __builtin_fmaf(-p, e, 1.0f);
    return copysignf(r, z);                   // v_bfi_b32
}

__device__ __forceinline__ float gelu_exact(float x) {
    return 0.5f * x * (1.0f + erf_fast(x * 0.70710678118654752440f));
}

// Load one 8-k-contiguous B fragment (bf16) from a row-major [K][ldn] fp32 weight,
// transposing on the fly: r[u] = W[k0+u][n].  B-operand mapping: n = lane&15, k = quad*8+u.
__device__ __forceinline__ short8 load_bfrag(const float* __restrict__ w, int k0, int n, int ldn) {
    short8 r;
#pragma unroll
    for (int u = 0; u < 8; ++u)
        r[u] = (short)f2bf(w[(k0 + u) * ldn + n]);
    return r;
}

// ---------------------------------------------------------------------------
// Head 1: structure predictor.
// per edge e: ef = [x[row], x[col]] (K=128); h = LN(ef@W1+b1)*g+be; out = gelu(h)@w2 + b2
// Tile: 128 edges x 256 cols, K=128.  8 waves in 2x4 grid, each wave 64x64.
// W1^T fragments live in registers (persistent across tiles); A (gathered edges) in LDS.
// ---------------------------------------------------------------------------
__global__ __launch_bounds__(512, 2)
void edge_head_kernel(const float* __restrict__ x, const int* __restrict__ ei,
                      const float* __restrict__ w1, const float* __restrict__ b1,
                      const float* __restrict__ g, const float* __restrict__ be,
                      const float* __restrict__ w2, const float* __restrict__ b2,
                      float* __restrict__ out, int E) {
    constexpr int KP = 136;                       // 128 + 8 pad: row stride 272B -> 2-way (free)
    __shared__ unsigned short sA[128 * KP];       // 34.8 KB gathered edge features (bf16)
    __shared__ float rsum[128 * 4];
    __shared__ float rssq[128 * 4];
    __shared__ float spL[128 * 4];

    const int tid = threadIdx.x;
    const int wave = tid >> 6, lane = tid & 63;
    const int l15 = lane & 15, quad = lane >> 4;
    const int rw = wave >> 2, cw = wave & 3;      // wave grid: 2 row-blocks x 4 col-blocks

    // persistent W1^T fragments: cols cw*64 + 16j + l15, K-slabs kk*32 + quad*8
    short8 breg[4][4];
#pragma unroll
    for (int j = 0; j < 4; ++j)
#pragma unroll
        for (int kk = 0; kk < 4; ++kk)
            breg[j][kk] = load_bfrag(w1, kk * 32 + quad * 8, cw * 64 + 16 * j + l15, 256);

    float b1v[4], gv[4], bev[4], w2v[4];
#pragma unroll
    for (int j = 0; j < 4; ++j) {
        int c = cw * 64 + 16 * j + l15;
        b1v[j] = b1[c]; gv[j] = g[c]; bev[j] = be[c]; w2v[j] = w2[c];
    }
    const float b2v = b2[0];

    const int ntiles = (E + 127) >> 7;
    const int eLoc = tid >> 2, p = tid & 3;       // 4 threads per edge, 32 floats each

    float4 pf[8];
    auto issue = [&](int t) {                     // prefetch gather for tile t into regs
        int e = t * 128 + eLoc; if (e >= E) e = E - 1;
        int idx = ei[(p >> 1) * E + e];           // p<2: row node, p>=2: col node
        const float4* src = (const float4*)(x + (long)idx * 64 + (p & 1) * 32);
#pragma unroll
        for (int u = 0; u < 8; ++u) pf[u] = src[u];
    };

    int t = blockIdx.x;
    if (t < ntiles) issue(t);
    for (; t < ntiles; t += gridDim.x) {
        // stage prefetched tile into LDS (bf16)
        unsigned short* dst = &sA[eLoc * KP + p * 32];
#pragma unroll
        for (int u = 0; u < 8; ++u) {
            ushort4 h;
            h.x = f2bf(pf[u].x); h.y = f2bf(pf[u].y);
            h.z = f2bf(pf[u].z); h.w = f2bf(pf[u].w);
            *(ushort4*)(dst + 4 * u) = h;
        }
        __syncthreads();                           // B1: sA ready
        if (t + (int)gridDim.x < ntiles) issue(t + (int)gridDim.x);  // overlap with MFMA

        f32x4 acc[4][4];
#pragma unroll
        for (int i = 0; i < 4; ++i)
#pragma unroll
            for (int j = 0; j < 4; ++j)
                acc[i][j] = (f32x4){0.f, 0.f, 0.f, 0.f};

#pragma unroll
        for (int kk = 0; kk < 4; ++kk) {
            short8 a[4];
#pragma unroll
            for (int i = 0; i < 4; ++i)
                a[i] = *(const short8*)&sA[(rw * 64 + 16 * i + l15) * KP + kk * 32 + quad * 8];
#pragma unroll
            for (int i = 0; i < 4; ++i)
#pragma unroll
                for (int j = 0; j < 4; ++j)
                    acc[i][j] = MFMA(a[i], breg[j][kk], acc[i][j]);
        }

        // per-row partial sums over this wave's 64 cols (LN stats span 4 col-waves)
#pragma unroll
        for (int i = 0; i < 4; ++i)
#pragma unroll
            for (int r = 0; r < 4; ++r) {
                float s = 0.f, ss = 0.f;
#pragma unroll
                for (int j = 0; j < 4; ++j) {
                    float v = acc[i][j][r] + b1v[j];
                    s += v; ss += v * v;
                }
#pragma unroll
                for (int m = 8; m >= 1; m >>= 1) {
                    s += __shfl_xor(s, m, 64);
                    ss += __shfl_xor(ss, m, 64);
                }
                if (l15 == 0) {
                    int row = rw * 64 + 16 * i + quad * 4 + r;   // C/D: row = quad*4+reg
                    rsum[row * 4 + cw] = s;
                    rssq[row * 4 + cw] = ss;
                }
            }
        __syncthreads();                           // B2: partials ready

#pragma unroll
        for (int i = 0; i < 4; ++i)
#pragma unroll
            for (int r = 0; r < 4; ++r) {
                int row = rw * 64 + 16 * i + quad * 4 + r;
                float s  = rsum[row*4+0] + rsum[row*4+1] + rsum[row*4+2] + rsum[row*4+3];
                float ss = rssq[row*4+0] + rssq[row*4+1] + rssq[row*4+2] + rssq[row*4+3];
                float mean = s * (1.f / 256.f);
                float var  = ss * (1.f / 256.f) - mean * mean;
                float rstd = rsqrtf(var + 1e-5f);
                float spp = 0.f;
#pragma unroll
                for (int j = 0; j < 4; ++j) {
                    float v = acc[i][j][r] + b1v[j];
                    float xn = (v - mean) * rstd * gv[j] + bev[j];
                    spp += gelu_exact(xn) * w2v[j];
                }
#pragma unroll
                for (int m = 8; m >= 1; m >>= 1)
                    spp += __shfl_xor(spp, m, 64);
                if (l15 == 0) spL[row * 4 + cw] = spp;
            }
        __syncthreads();                           // B3: spL ready

        int e = t * 128 + tid;
        if (tid < 128 && e < E)
            out[e] = spL[tid*4+0] + spL[tid*4+1] + spL[tid*4+2] + spL[tid*4+3] + b2v;
    }
}

// ---------------------------------------------------------------------------
// Heads 2/3: fused row-MLP  out = gelu(LN(x@W1+b1)*g+be) @ W2 + b2
// Tile 64 rows; 4 waves each own N1/4 cols of GEMM1 and N2/4 cols of GEMM2.
// Both weights' fragments cached in registers; LDS holds A-tile then gelu(h) (A-layout).
// ---------------------------------------------------------------------------
template<int K, int N1, int N2>
__global__ __launch_bounds__(256, 2)
void mlp_head_kernel(const float* __restrict__ x,
                     const float* __restrict__ w1, const float* __restrict__ b1,
                     const float* __restrict__ g, const float* __restrict__ be,
                     const float* __restrict__ w2, const float* __restrict__ b2,
                     float* __restrict__ out, int Nrows) {
    constexpr int KP   = K + 8;
    constexpr int N1P  = N1 + 8;
    constexpr int JT1  = N1 / 64;     // GEMM1 col-tiles per wave
    constexpr int JT2  = N2 / 64 > 0 ? N2 / 64 : 1;
    constexpr int CPW1 = N1 / 4;
    constexpr int CPW2 = N2 / 4;
    constexpr int KK1  = K / 32;
    constexpr int KK2  = N1 / 32;

    __shared__ unsigned short sS[64 * N1P];   // union: A [64][KP] then gelu(h) [64][N1P]
    __shared__ float rsum[64 * 4], rssq[64 * 4];

    const int tid = threadIdx.x;
    const int wave = tid >> 6, lane = tid & 63;
    const int l15 = lane & 15, quad = lane >> 4;

    short8 breg1[JT1][KK1];
#pragma unroll
    for (int j = 0; j < JT1; ++j)
#pragma unroll
        for (int kk = 0; kk < KK1; ++kk)
            breg1[j][kk] = load_bfrag(w1, kk * 32 + quad * 8, CPW1 * wave + 16 * j + l15, N1);
    short8 breg2[JT2][KK2];
#pragma unroll
    for (int j = 0; j < JT2; ++j)
#pragma unroll
        for (int kk = 0; kk < KK2; ++kk)
            breg2[j][kk] = load_bfrag(w2, kk * 32 + quad * 8, CPW2 * wave + 16 * j + l15, N2);

    float b1v[JT1], gv[JT1], bev[JT1];
#pragma unroll
    for (int j = 0; j < JT1; ++j) {
        int c = CPW1 * wave + 16 * j + l15;
        b1v[j] = b1[c]; gv[j] = g[c]; bev[j] = be[c];
    }
    float b2v[JT2];
#pragma unroll
    for (int j = 0; j < JT2; ++j) b2v[j] = b2[CPW2 * wave + 16 * j + l15];

    const int ntiles = (Nrows + 63) >> 6;
    const int m0 = tid >> 2, p = tid & 3;     // 4 threads per row for A staging

    for (int t = blockIdx.x; t < ntiles; t += gridDim.x) {
        const int r0 = t << 6;
        __syncthreads();                       // B0: prev-iter GEMM2 reads of sS done
        {
            int rowg = r0 + m0; if (rowg >= Nrows) rowg = Nrows - 1;
            const float4* src = (const float4*)(x + (long)rowg * K + p * (K / 4));
            unsigned short* dst = &sS[m0 * KP + p * (K / 4)];
#pragma unroll
            for (int u = 0; u < K / 16; ++u) {
                float4 f = src[u];
                ushort4 h; h.x = f2bf(f.x); h.y = f2bf(f.y); h.z = f2bf(f.z); h.w = f2bf(f.w);
                *(ushort4*)(dst + 4 * u) = h;
            }
        }
        __syncthreads();                       // B1: A ready

        f32x4 acc1[4][JT1];
#pragma unroll
        for (int i = 0; i < 4; ++i)
#pragma unroll
            for (int j = 0; j < JT1; ++j)
                acc1[i][j] = (f32x4){0.f, 0.f, 0.f, 0.f};

#pragma unroll
        for (int kk = 0; kk < KK1; ++kk) {
            short8 a[4];
#pragma unroll
            for (int i = 0; i < 4; ++i)
                a[i] = *(const short8*)&sS[(16 * i + l15) * KP + kk * 32 + quad * 8];
#pragma unroll
            for (int i = 0; i < 4; ++i)
#pragma unroll
                for (int j = 0; j < JT1; ++j)
                    acc1[i][j] = MFMA(a[i], breg1[j][kk], acc1[i][j]);
        }

#pragma unroll
        for (int i = 0; i < 4; ++i)
#pragma unroll
            for (int r = 0; r < 4; ++r) {
                float s = 0.f, ss = 0.f;
#pragma unroll
                for (int j = 0; j < JT1; ++j) {
                    float v = acc1[i][j][r] + b1v[j];
                    s += v; ss += v * v;
                }
#pragma unroll
                for (int m = 8; m >= 1; m >>= 1) {
                    s += __shfl_xor(s, m, 64);
                    ss += __shfl_xor(ss, m, 64);
                }
                if (l15 == 0) {
                    int row = 16 * i + quad * 4 + r;
                    rsum[row * 4 + wave] = s; rssq[row * 4 + wave] = ss;
                }
            }
        __syncthreads();                       // B2: LN partials ready (A also fully consumed)

#pragma unroll
        for (int i = 0; i < 4; ++i)
#pragma unroll
            for (int r = 0; r < 4; ++r) {
                int row = 16 * i + quad * 4 + r;
                float s  = rsum[row*4+0] + rsum[row*4+1] + rsum[row*4+2] + rsum[row*4+3];
                float ss = rssq[row*4+0] + rssq[row*4+1] + rssq[row*4+2] + rssq[row*4+3];
                float mean = s * (1.f / (float)N1);
                float var  = ss * (1.f / (float)N1) - mean * mean;
                float rstd = rsqrtf(var + 1e-5f);
#pragma unroll
                for (int j = 0; j < JT1; ++j) {
                    float v = acc1[i][j][r] + b1v[j];
                    float xn = (v - mean) * rstd * gv[j] + bev[j];
                    sS[row * N1P + CPW1 * wave + 16 * j + l15] = f2bf(gelu_exact(xn));
                }
            }
        __syncthreads();                       // B3: gelu(h) ready in A-layout

        f32x4 acc2[4][JT2];
#pragma unroll
        for (int i = 0; i < 4; ++i)
#pragma unroll
            for (int j = 0; j < JT2; ++j)
                acc2[i][j] = (f32x4){0.f, 0.f, 0.f, 0.f};

#pragma unroll
        for (int kk = 0; kk < KK2; ++kk) {
            short8 a[4];
#pragma unroll
            for (int i = 0; i < 4; ++i)
                a[i] = *(const short8*)&sS[(16 * i + l15) * N1P + kk * 32 + quad * 8];
#pragma unroll
            for (int i = 0; i < 4; ++i)
#pragma unroll
                for (int j = 0; j < JT2; ++j)
                    acc2[i][j] = MFMA(a[i], breg2[j][kk], acc2[i][j]);
        }

#pragma unroll
        for (int i = 0; i < 4; ++i)
#pragma unroll
            for (int r = 0; r < 4; ++r) {
                int rowg = r0 + 16 * i + quad * 4 + r;
                if (rowg < Nrows) {
#pragma unroll
                    for (int j = 0; j < JT2; ++j)
                        out[(long)rowg * N2 + CPW2 * wave + 16 * j + l15] = acc2[i][j][r] + b2v[j];
                }
            }
    }
}

extern "C" void kernel_launch(void* const* d_in, const int* in_sizes, int n_in,
                              void* d_out, int out_size, void* d_ws, size_t ws_size,
                              hipStream_t stream) {
    const float* x     = (const float*)d_in[0];
    const int*   ei    = (const int*)d_in[1];
    const float* sp_w1 = (const float*)d_in[2];
    const float* sp_b1 = (const float*)d_in[3];
    const float* sp_g  = (const float*)d_in[4];
    const float* sp_be = (const float*)d_in[5];
    const float* sp_w2 = (const float*)d_in[6];
    const float* sp_b2 = (const float*)d_in[7];
    const float* fr_w1 = (const float*)d_in[8];
    const float* fr_b1 = (const float*)d_in[9];
    const float* fr_g  = (const float*)d_in[10];
    const float* fr_be = (const float*)d_in[11];
    const float* fr_w2 = (const float*)d_in[12];
    const float* fr_b2 = (const float*)d_in[13];
    const float* ph_w1 = (const float*)d_in[14];
    const float* ph_b1 = (const float*)d_in[15];
    const float* ph_g  = (const float*)d_in[16];
    const float* ph_be = (const float*)d_in[17];
    const float* ph_w2 = (const float*)d_in[18];
    const float* ph_b2 = (const float*)d_in[19];

    const int N = in_sizes[0] / 64;
    const int E = in_sizes[1] / 2;

    float* out_sp   = (float*)d_out;
    float* out_rec  = out_sp + E;
    float* out_proj = out_rec + (size_t)N * 64;

    int etiles = (E + 127) / 128;
    int egrid  = etiles < 1024 ? etiles : 1024;
    edge_head_kernel<<<dim3(egrid), dim3(512), 0, stream>>>(
        x, ei, sp_w1, sp_b1, sp_g, sp_be, sp_w2, sp_b2, out_sp, E);

    int mtiles = (N + 63) / 64;
    int mgrid  = mtiles < 256 ? mtiles : 256;
    mlp_head_kernel<64, 128, 64><<<dim3(mgrid), dim3(256), 0, stream>>>(
        x, fr_w1, fr_b1, fr_g, fr_be, fr_w2, fr_b2, out_rec, N);
    mlp_head_kernel<64, 256, 128><<<dim3(mgrid), dim3(256), 0, stream>>>(
        x, ph_w1, ph_b1, ph_g, ph_be, ph_w2, ph_b2, out_proj, N);
}

// Round 3
// 404.126 us; speedup vs baseline: 1.5205x; 1.3585x over previous
//
#include <hip/hip_runtime.h>
#include <hip/hip_bf16.h>

typedef __attribute__((ext_vector_type(8))) short short8;   // 8 bf16 = 4 VGPRs (MFMA A/B frag)
typedef __attribute__((ext_vector_type(4))) float f32x4;    // MFMA C/D frag

#define MFMA(a, b, c) __builtin_amdgcn_mfma_f32_16x16x32_bf16((a), (b), (c), 0, 0, 0)

__device__ __forceinline__ unsigned short f2bf(float f) {
    unsigned int u = __float_as_uint(f);
    u += 0x7fffu + ((u >> 16) & 1u);          // round-to-nearest-even
    return (unsigned short)(u >> 16);
}

// 16-lane sum via DPP row_ror (VALU-only, no ds_swizzle). After 4 steps every
// lane in each 16-lane row holds the full sum.
template<int CTRL>
__device__ __forceinline__ float dpp_addf(float v) {
    int t = __builtin_amdgcn_update_dpp(0, __float_as_int(v), CTRL, 0xF, 0xF, true);
    return v + __int_as_float(t);
}
__device__ __forceinline__ float rowsum16(float v) {
    v = dpp_addf<0x121>(v);   // row_ror:1
    v = dpp_addf<0x122>(v);   // row_ror:2
    v = dpp_addf<0x124>(v);   // row_ror:4
    v = dpp_addf<0x128>(v);   // row_ror:8
    return v;
}

// gelu tanh-form: 0.5x(1+tanh(0.79788456(x+0.044715x^3))) == x*E/(E+1),
// E = exp(x*(1.59576912 + 0.07135533 x^2)).  |err vs exact erf-gelu| <= ~3e-4.
// clamp +-8 guards exp overflow (x beyond +-8 saturates exactly anyway).
__device__ __forceinline__ float gelu_fast(float x) {
    x = __builtin_amdgcn_fmed3f(x, -8.0f, 8.0f);
    float a = x * __builtin_fmaf(x * x, 0.07135533f, 1.59576912f);
    float E = __expf(a);
    float r = __builtin_amdgcn_rcpf(E + 1.0f);
    return x * E * r;
}

// Load one 8-k-contiguous B fragment (bf16) from a row-major [K][ldn] fp32 weight,
// transposing on the fly: r[u] = W[k0+u][n].  B-operand mapping: n = lane&15, k = quad*8+u.
__device__ __forceinline__ short8 load_bfrag(const float* __restrict__ w, int k0, int n, int ldn) {
    short8 r;
#pragma unroll
    for (int u = 0; u < 8; ++u)
        r[u] = (short)f2bf(w[(k0 + u) * ldn + n]);
    return r;
}

struct SmemEdge {
    unsigned short sA[128 * 136];   // gathered edge features, KP=136 pad (2-way = free)
    float rstat[128 * 8];           // (s,ss) float2 per row per col-wave
    float spL[128 * 4];
};
template<int N1P>
struct SmemMlp {
    unsigned short sS[64 * N1P];    // union: A [64][K+8] then gelu(h) [64][N1P]
    float rstat[64 * 8];
};
union SmemU {
    SmemEdge e;
    SmemMlp<136> a;   // head A: N1=128
    SmemMlp<264> b;   // head B: N1=256
};

// ---------------------------------------------------------------------------
// Edge head: per edge ef=[x[row],x[col]] (K=128); h=LN(ef@W1+b1)*g+be; out=gelu(h)@w2+b2
// Tile 128 edges x 256 cols; 8 waves (2 row x 4 col), W1^T frags persistent in regs.
// ---------------------------------------------------------------------------
__device__ void edge_role(SmemEdge& sm, const float* __restrict__ x, const int* __restrict__ ei,
                          const float* __restrict__ w1, const float* __restrict__ b1,
                          const float* __restrict__ g, const float* __restrict__ be,
                          const float* __restrict__ w2, const float* __restrict__ b2,
                          float* __restrict__ out, int E, int bid, int nblocks) {
    constexpr int KP = 136;
    const int tid = threadIdx.x;
    const int wave = tid >> 6, lane = tid & 63;
    const int l15 = lane & 15, quad = lane >> 4;
    const int rw = wave >> 2, cw = wave & 3;

    short8 breg[4][4];
#pragma unroll
    for (int j = 0; j < 4; ++j)
#pragma unroll
        for (int kk = 0; kk < 4; ++kk)
            breg[j][kk] = load_bfrag(w1, kk * 32 + quad * 8, cw * 64 + 16 * j + l15, 256);

    float b1v[4], gv[4], bev[4], w2v[4];
#pragma unroll
    for (int j = 0; j < 4; ++j) {
        int c = cw * 64 + 16 * j + l15;
        b1v[j] = b1[c]; gv[j] = g[c]; bev[j] = be[c]; w2v[j] = w2[c];
    }
    const float b2v = b2[0];

    const int ntiles = (E + 127) >> 7;
    const int eLoc = tid >> 2, p = tid & 3;       // 4 threads per edge, 32 floats each

    float4 pf[8];
    auto issue = [&](int t) {                     // prefetch gather for tile t into regs
        int e = t * 128 + eLoc; if (e >= E) e = E - 1;
        int idx = ei[(p >> 1) * E + e];           // p<2: row node, p>=2: col node
        const float4* src = (const float4*)(x + (long)idx * 64 + (p & 1) * 32);
#pragma unroll
        for (int u = 0; u < 8; ++u) pf[u] = src[u];
    };

    int t = bid;
    if (t < ntiles) issue(t);
    for (; t < ntiles; t += nblocks) {
        unsigned short* dst = &sm.sA[eLoc * KP + p * 32];
#pragma unroll
        for (int u = 0; u < 8; ++u) {
            ushort4 h;
            h.x = f2bf(pf[u].x); h.y = f2bf(pf[u].y);
            h.z = f2bf(pf[u].z); h.w = f2bf(pf[u].w);
            *(ushort4*)(dst + 4 * u) = h;
        }
        __syncthreads();                           // B1: sA ready
        if (t + nblocks < ntiles) issue(t + nblocks);  // overlap with MFMA

        f32x4 acc[4][4];
#pragma unroll
        for (int i = 0; i < 4; ++i)
#pragma unroll
            for (int j = 0; j < 4; ++j)
                acc[i][j] = (f32x4){0.f, 0.f, 0.f, 0.f};

#pragma unroll
        for (int kk = 0; kk < 4; ++kk) {
            short8 a[4];
#pragma unroll
            for (int i = 0; i < 4; ++i)
                a[i] = *(const short8*)&sm.sA[(rw * 64 + 16 * i + l15) * KP + kk * 32 + quad * 8];
#pragma unroll
            for (int i = 0; i < 4; ++i)
#pragma unroll
                for (int j = 0; j < 4; ++j)
                    acc[i][j] = MFMA(a[i], breg[j][kk], acc[i][j]);
        }

        // pass A: v = acc + b1 in place; per-row (s,ss) partials via DPP
#pragma unroll
        for (int i = 0; i < 4; ++i)
#pragma unroll
            for (int r = 0; r < 4; ++r) {
                float v0 = acc[i][0][r] + b1v[0];
                float v1 = acc[i][1][r] + b1v[1];
                float v2 = acc[i][2][r] + b1v[2];
                float v3 = acc[i][3][r] + b1v[3];
                acc[i][0][r] = v0; acc[i][1][r] = v1; acc[i][2][r] = v2; acc[i][3][r] = v3;
                float s  = (v0 + v1) + (v2 + v3);
                float ss = __builtin_fmaf(v0, v0, __builtin_fmaf(v1, v1,
                           __builtin_fmaf(v2, v2, v3 * v3)));
                s = rowsum16(s); ss = rowsum16(ss);
                if (l15 == 0) {
                    int row = rw * 64 + 16 * i + quad * 4 + r;   // C/D: row = quad*4+reg
                    *(float2*)&sm.rstat[row * 8 + cw * 2] = make_float2(s, ss);
                }
            }
        __syncthreads();                           // B2: partials ready

#pragma unroll
        for (int i = 0; i < 4; ++i)
#pragma unroll
            for (int r = 0; r < 4; ++r) {
                int row = rw * 64 + 16 * i + quad * 4 + r;
                const float4* st = (const float4*)&sm.rstat[row * 8];
                float4 q0 = st[0], q1 = st[1];
                float s  = (q0.x + q0.z) + (q1.x + q1.z);
                float ss = (q0.y + q0.w) + (q1.y + q1.w);
                float mean = s * (1.f / 256.f);
                float var  = __builtin_fmaf(ss, 1.f / 256.f, -mean * mean);
                float rstd = __builtin_amdgcn_rsqf(var + 1e-5f);
                float nm = -mean * rstd;
                float spp = 0.f;
#pragma unroll
                for (int j = 0; j < 4; ++j) {
                    float tt = __builtin_fmaf(acc[i][j][r], rstd, nm);
                    float xn = __builtin_fmaf(tt, gv[j], bev[j]);
                    spp = __builtin_fmaf(gelu_fast(xn), w2v[j], spp);
                }
                spp = rowsum16(spp);
                if (l15 == 0) sm.spL[row * 4 + cw] = spp;
            }
        __syncthreads();                           // B3: spL ready

        int e = t * 128 + tid;
        if (tid < 128 && e < E)
            out[e] = sm.spL[tid*4+0] + sm.spL[tid*4+1] + sm.spL[tid*4+2] + sm.spL[tid*4+3] + b2v;
    }
}

// ---------------------------------------------------------------------------
// MLP heads: out = gelu(LN(x@W1+b1)*g+be) @ W2 + b2.  256 active threads (4 waves);
// waves 4..7 return before any barrier (HW excludes exited waves from s_barrier).
// breg2 loaded per-tile post-B3 to keep merged-kernel VGPR peak at the edge level.
// ---------------------------------------------------------------------------
template<int K, int N1, int N2>
__device__ void mlp_role(SmemMlp<N1 + 8>& sm, const float* __restrict__ x,
                         const float* __restrict__ w1, const float* __restrict__ b1,
                         const float* __restrict__ g, const float* __restrict__ be,
                         const float* __restrict__ w2, const float* __restrict__ b2,
                         float* __restrict__ out, int Nrows, int bid, int nblocks) {
    constexpr int KP = K + 8, N1P = N1 + 8;
    constexpr int JT1 = N1 / 64;
    constexpr int JT2 = (N2 >= 64) ? N2 / 64 : 1;
    constexpr int CPW1 = N1 / 4, CPW2 = N2 / 4;
    constexpr int KK1 = K / 32, KK2 = N1 / 32;

    const int tid = threadIdx.x;
    if (tid >= 256) return;
    const int wave = tid >> 6, lane = tid & 63;
    const int l15 = lane & 15, quad = lane >> 4;

    short8 breg1[JT1][KK1];
#pragma unroll
    for (int j = 0; j < JT1; ++j)
#pragma unroll
        for (int kk = 0; kk < KK1; ++kk)
            breg1[j][kk] = load_bfrag(w1, kk * 32 + quad * 8, CPW1 * wave + 16 * j + l15, N1);

    float b1v[JT1], gv[JT1], bev[JT1];
#pragma unroll
    for (int j = 0; j < JT1; ++j) {
        int c = CPW1 * wave + 16 * j + l15;
        b1v[j] = b1[c]; gv[j] = g[c]; bev[j] = be[c];
    }
    float b2v[JT2];
#pragma unroll
    for (int j = 0; j < JT2; ++j) b2v[j] = b2[CPW2 * wave + 16 * j + l15];

    const int ntiles = (Nrows + 63) >> 6;
    const int m0 = tid >> 2, p = tid & 3;

    for (int t = bid; t < ntiles; t += nblocks) {
        const int r0 = t << 6;
        __syncthreads();                       // B0: prev GEMM2 reads of sS done
        {
            int rowg = r0 + m0; if (rowg >= Nrows) rowg = Nrows - 1;
            const float4* src = (const float4*)(x + (long)rowg * K + p * (K / 4));
            unsigned short* dst = &sm.sS[m0 * KP + p * (K / 4)];
#pragma unroll
            for (int u = 0; u < K / 16; ++u) {
                float4 f = src[u];
                ushort4 h; h.x = f2bf(f.x); h.y = f2bf(f.y); h.z = f2bf(f.z); h.w = f2bf(f.w);
                *(ushort4*)(dst + 4 * u) = h;
            }
        }
        __syncthreads();                       // B1: A ready

        f32x4 acc1[4][JT1];
#pragma unroll
        for (int i = 0; i < 4; ++i)
#pragma unroll
            for (int j = 0; j < JT1; ++j)
                acc1[i][j] = (f32x4){0.f, 0.f, 0.f, 0.f};

#pragma unroll
        for (int kk = 0; kk < KK1; ++kk) {
            short8 a[4];
#pragma unroll
            for (int i = 0; i < 4; ++i)
                a[i] = *(const short8*)&sm.sS[(16 * i + l15) * KP + kk * 32 + quad * 8];
#pragma unroll
            for (int i = 0; i < 4; ++i)
#pragma unroll
                for (int j = 0; j < JT1; ++j)
                    acc1[i][j] = MFMA(a[i], breg1[j][kk], acc1[i][j]);
        }

        // pass A: bias in place + (s,ss) partials via DPP
#pragma unroll
        for (int i = 0; i < 4; ++i)
#pragma unroll
            for (int r = 0; r < 4; ++r) {
                float s = 0.f, ss = 0.f;
#pragma unroll
                for (int j = 0; j < JT1; ++j) {
                    float v = acc1[i][j][r] + b1v[j];
                    acc1[i][j][r] = v;
                    s += v; ss = __builtin_fmaf(v, v, ss);
                }
                s = rowsum16(s); ss = rowsum16(ss);
                if (l15 == 0) {
                    int row = 16 * i + quad * 4 + r;
                    *(float2*)&sm.rstat[row * 8 + wave * 2] = make_float2(s, ss);
                }
            }
        __syncthreads();                       // B2: partials ready (GEMM1 sS reads done)

#pragma unroll
        for (int i = 0; i < 4; ++i)
#pragma unroll
            for (int r = 0; r < 4; ++r) {
                int row = 16 * i + quad * 4 + r;
                const float4* st = (const float4*)&sm.rstat[row * 8];
                float4 q0 = st[0], q1 = st[1];
                float s  = (q0.x + q0.z) + (q1.x + q1.z);
                float ss = (q0.y + q0.w) + (q1.y + q1.w);
                float mean = s * (1.f / (float)N1);
                float var  = __builtin_fmaf(ss, 1.f / (float)N1, -mean * mean);
                float rstd = __builtin_amdgcn_rsqf(var + 1e-5f);
                float nm = -mean * rstd;
#pragma unroll
                for (int j = 0; j < JT1; ++j) {
                    float tt = __builtin_fmaf(acc1[i][j][r], rstd, nm);
                    float xn = __builtin_fmaf(tt, gv[j], bev[j]);
                    sm.sS[row * N1P + CPW1 * wave + 16 * j + l15] = f2bf(gelu_fast(xn));
                }
            }
        __syncthreads();                       // B3: gelu(h) ready in A-layout

        short8 breg2[JT2][KK2];
#pragma unroll
        for (int j = 0; j < JT2; ++j)
#pragma unroll
            for (int kk = 0; kk < KK2; ++kk)
                breg2[j][kk] = load_bfrag(w2, kk * 32 + quad * 8, CPW2 * wave + 16 * j + l15, N2);

        f32x4 acc2[4][JT2];
#pragma unroll
        for (int i = 0; i < 4; ++i)
#pragma unroll
            for (int j = 0; j < JT2; ++j)
                acc2[i][j] = (f32x4){0.f, 0.f, 0.f, 0.f};

#pragma unroll
        for (int kk = 0; kk < KK2; ++kk) {
            short8 a[4];
#pragma unroll
            for (int i = 0; i < 4; ++i)
                a[i] = *(const short8*)&sm.sS[(16 * i + l15) * N1P + kk * 32 + quad * 8];
#pragma unroll
            for (int i = 0; i < 4; ++i)
#pragma unroll
                for (int j = 0; j < JT2; ++j)
                    acc2[i][j] = MFMA(a[i], breg2[j][kk], acc2[i][j]);
        }

#pragma unroll
        for (int i = 0; i < 4; ++i)
#pragma unroll
            for (int r = 0; r < 4; ++r) {
                int rowg = r0 + 16 * i + quad * 4 + r;
                if (rowg < Nrows) {
#pragma unroll
                    for (int j = 0; j < JT2; ++j)
                        out[(long)rowg * N2 + CPW2 * wave + 16 * j + l15] = acc2[i][j][r] + b2v[j];
                }
            }
    }
}

// Merged kernel: MLP blocks dispatch FIRST (0..511) so they overlap the edge work.
__global__ __launch_bounds__(512, 2)
void fused_all(const float* __restrict__ x, const int* __restrict__ ei,
               const float* __restrict__ sp_w1, const float* __restrict__ sp_b1,
               const float* __restrict__ sp_g, const float* __restrict__ sp_be,
               const float* __restrict__ sp_w2, const float* __restrict__ sp_b2,
               const float* __restrict__ fr_w1, const float* __restrict__ fr_b1,
               const float* __restrict__ fr_g, const float* __restrict__ fr_be,
               const float* __restrict__ fr_w2, const float* __restrict__ fr_b2,
               const float* __restrict__ ph_w1, const float* __restrict__ ph_b1,
               const float* __restrict__ ph_g, const float* __restrict__ ph_be,
               const float* __restrict__ ph_w2, const float* __restrict__ ph_b2,
               float* __restrict__ out_sp, float* __restrict__ out_rec,
               float* __restrict__ out_proj, int N, int E) {
    __shared__ SmemU sm;
    const int b = blockIdx.x;
    if (b < 256) {
        mlp_role<64, 128, 64>(sm.a, x, fr_w1, fr_b1, fr_g, fr_be, fr_w2, fr_b2,
                              out_rec, N, b, 256);
    } else if (b < 512) {
        mlp_role<64, 256, 128>(sm.b, x, ph_w1, ph_b1, ph_g, ph_be, ph_w2, ph_b2,
                               out_proj, N, b - 256, 256);
    } else {
        edge_role(sm.e, x, ei, sp_w1, sp_b1, sp_g, sp_be, sp_w2, sp_b2,
                  out_sp, E, b - 512, 1024);
    }
}

extern "C" void kernel_launch(void* const* d_in, const int* in_sizes, int n_in,
                              void* d_out, int out_size, void* d_ws, size_t ws_size,
                              hipStream_t stream) {
    const float* x     = (const float*)d_in[0];
    const int*   ei    = (const int*)d_in[1];

    const int N = in_sizes[0] / 64;
    const int E = in_sizes[1] / 2;

    float* out_sp   = (float*)d_out;
    float* out_rec  = out_sp + E;
    float* out_proj = out_rec + (size_t)N * 64;

    fused_all<<<dim3(1536), dim3(512), 0, stream>>>(
        x, ei,
        (const float*)d_in[2],  (const float*)d_in[3],  (const float*)d_in[4],
        (const float*)d_in[5],  (const float*)d_in[6],  (const float*)d_in[7],
        (const float*)d_in[8],  (const float*)d_in[9],  (const float*)d_in[10],
        (const float*)d_in[11], (const float*)d_in[12], (const float*)d_in[13],
        (const float*)d_in[14], (const float*)d_in[15], (const float*)d_in[16],
        (const float*)d_in[17], (const float*)d_in[18], (const float*)d_in[19],
        out_sp, out_rec, out_proj, N, E);
}